// Round 1
// baseline (189.453 us; speedup 1.0000x reference)
//
#include <hip/hip_runtime.h>
#include <stdint.h>

// ---- problem constants ----
#define NH      4
#define SF      128
#define BF      256
#define HD      32
#define NB      256    // WU*WU big tokens
#define NS      64     // W*W small tokens
#define NBATCH  1024

typedef short bf16x8 __attribute__((ext_vector_type(8)));
typedef float f32x4  __attribute__((ext_vector_type(4)));

// ---- ws layout (bytes) ----
#define WEFFT_OFF 0        // short[128*256]  (WeffT[n][k], scale*log2e folded)
#define BEFF_OFF  65536    // float[128]
#define WKVT_OFF  66048    // short[256*128]  (WkvT[n][k]; n<128 K-proj, n>=128 V-proj)
#define W2T_OFF   131584   // short[256*128]  (W2T[n][k])
#define BMATT_OFF 197120   // float[4*64*256] (BmatT[h][key][q] * log2e)

// ---- LDS layout (bytes), total 81920 ----
#define LDS_SK  0          // 16KB: small_x stage -> K  [64 tok][128 f] bf16, swz256
#define LDS_SVT 16384      // 16KB: V^T [128 f][64 tok] bf16, swz128
#define LDS_SQ  32768      // 32KB: Q [128 q][128 f] bf16, swz256; later sP (8KB/wave)
#define LDS_STG 65536      // 16KB: big_x chunk [128 q][64 k] bf16, swz128
#define LDS_TOTAL 81920

__device__ __forceinline__ short f2b(float x){
  uint32_t u = __float_as_uint(x);
  u += 0x7fff + ((u >> 16) & 1);
  return (short)(u >> 16);
}
__device__ __forceinline__ uint32_t cvt_pk_bf16(float lo, float hi){
  uint32_t r;
  asm("v_cvt_pk_bf16_f32 %0, %1, %2" : "=v"(r) : "v"(lo), "v"(hi));
  return r;
}
__device__ __forceinline__ int swz256(int row, int byteInRow){
  return row * 256 + (byteInRow ^ ((row & 7) << 4));
}
__device__ __forceinline__ int swz128(int row, int byteInRow){
  return row * 128 + (byteInRow ^ ((row & 7) << 4));
}

// =====================================================================
// prep: WeffT = (W1 @ Wqkv[:, :SF])^T * SCALE*log2e (bf16),
//       beff, WkvT (bf16), W2T (bf16), BmatT[h][key][q]*log2e (f32)
// grid: 417 x 256
// =====================================================================
__global__ void cowin_prep(const float* __restrict__ W1, const float* __restrict__ b1,
                           const float* __restrict__ Wqkv, const float* __restrict__ bqkv,
                           const float* __restrict__ W2, const float* __restrict__ tbl,
                           void* ws)
{
  short* weffT = (short*)((char*)ws + WEFFT_OFF);
  float* beff  = (float*)((char*)ws + BEFF_OFF);
  short* wkvT  = (short*)((char*)ws + WKVT_OFF);
  short* w2T   = (short*)((char*)ws + W2T_OFF);
  float* bmatT = (float*)((char*)ws + BMATT_OFF);
  const float L2E = 1.4426950408889634f;
  const float QS  = 0.17677669529663687f * L2E;   // HD^-0.5 * log2e

  int bid = blockIdx.x, t = threadIdx.x;
  if (bid < 128){                        // WeffT: n = bid, k = t
    int n = bid, k = t;
    float acc = 0.f;
    for (int c = 0; c < SF; ++c) acc += W1[k * SF + c] * Wqkv[c * (3*SF) + n];
    weffT[n * 256 + k] = f2b(acc * QS);
  } else if (bid == 128){
    if (t < 128){
      int n = t;
      float acc = bqkv[n];
      for (int c = 0; c < SF; ++c) acc += b1[c] * Wqkv[c * (3*SF) + n];
      beff[n] = acc * QS;
    }
  } else if (bid < 145){                 // WkvT: 32768 elems
    int base = (bid - 129) * 2048 + t * 8;
    for (int j = 0; j < 8; ++j){
      int i = base + j, n = i >> 7, k = i & 127;
      wkvT[i] = f2b(Wqkv[k * (3*SF) + SF + n]);
    }
  } else if (bid < 161){                 // W2T: 32768 elems
    int base = (bid - 145) * 2048 + t * 8;
    for (int j = 0; j < 8; ++j){
      int i = base + j, n = i >> 7, k = i & 127;
      w2T[i] = f2b(W2[k * BF + n]);
    }
  } else {                               // BmatT: 65536 elems
    int i = (bid - 161) * 256 + t;
    int h = i >> 14, kk = (i >> 8) & 63, q = i & 255;
    int qh = q >> 4, qw = q & 15, kh = kk >> 3, kw = kk & 7;
    int idx = (qh - kh + 7) * 15 + (qw - kw + 7);
    bmatT[i] = tbl[idx * 4 + h] * L2E;
  }
}

// =====================================================================
// fused main: one block = (batch b, row-half hf). 256 thr = 4 waves.
// =====================================================================
__global__ __launch_bounds__(256, 2) void cowin_main(
    const float* __restrict__ big_x, const float* __restrict__ small_x,
    const float* __restrict__ bqkv,  const float* __restrict__ b2,
    const void* __restrict__ ws, float* __restrict__ out)
{
  extern __shared__ char smem[];
  const short* weffT = (const short*)((const char*)ws + WEFFT_OFF);
  const float* beff  = (const float*)((const char*)ws + BEFF_OFF);
  const short* wkvT  = (const short*)((const char*)ws + WKVT_OFF);
  const short* w2T   = (const short*)((const char*)ws + W2T_OFF);
  const float* bmatT = (const float*)((const char*)ws + BMATT_OFF);

  const int bid = blockIdx.x;
  const int b  = bid >> 1;
  const int hf = bid & 1;
  const int t    = threadIdx.x;
  const int w    = t >> 6;          // wave id = head id in attn phases
  const int lane = t & 63;
  const int li   = lane & 15;       // within-tile row/col
  const int g    = lane >> 4;       // lane quarter

  const f32x4 vzero = {0.f, 0.f, 0.f, 0.f};

  // ---------- Phase A: stage small_x -> sX (sK region), bf16, swizzled ----------
  {
    const float* sx = small_x + (size_t)b * (NS * SF);
    int tok = t >> 2, q4 = t & 3;
    const float4* src = (const float4*)(sx + tok * SF + q4 * 32);
    float4 v[8];
    #pragma unroll
    for (int j = 0; j < 8; ++j) v[j] = src[j];
    uint32_t pk[16];
    #pragma unroll
    for (int j = 0; j < 8; ++j){
      pk[2*j]   = cvt_pk_bf16(v[j].x, v[j].y);
      pk[2*j+1] = cvt_pk_bf16(v[j].z, v[j].w);
    }
    #pragma unroll
    for (int c = 0; c < 4; ++c){
      uint4 u; u.x = pk[c*4]; u.y = pk[c*4+1]; u.z = pk[c*4+2]; u.w = pk[c*4+3];
      *(uint4*)(smem + LDS_SK + swz256(tok, q4 * 64 + c * 16)) = u;
    }
  }
  __syncthreads();

  // ---------- Phase B: KV GEMM: [64 tok] x [256 n] = sX @ Wkv ----------
  f32x4 kv[4][4];
  #pragma unroll
  for (int m = 0; m < 4; ++m)
    #pragma unroll
    for (int n = 0; n < 4; ++n) kv[m][n] = vzero;

  #pragma unroll
  for (int ks = 0; ks < 4; ++ks){
    bf16x8 afr[4];
    #pragma unroll
    for (int m = 0; m < 4; ++m)
      afr[m] = *(const bf16x8*)(smem + LDS_SK + swz256(m*16 + li, (ks*32 + g*8) * 2));
    #pragma unroll
    for (int n4 = 0; n4 < 4; ++n4){
      int n = w * 64 + n4 * 16 + li;
      bf16x8 bfr = *(const bf16x8*)(wkvT + n * 128 + ks * 32 + g * 8);
      #pragma unroll
      for (int m = 0; m < 4; ++m)
        kv[m][n4] = __builtin_amdgcn_mfma_f32_16x16x32_bf16(afr[m], bfr, kv[m][n4], 0, 0, 0);
    }
  }
  __syncthreads();   // all sX reads done

  // ---------- Phase C: waves 0,1 write K [tok][feat]; waves 2,3 write V^T [feat][tok] ----------
  if (w < 2){
    #pragma unroll
    for (int n4 = 0; n4 < 4; ++n4){
      int feat = w * 64 + n4 * 16 + li;          // 0..127
      float bias = bqkv[SF + feat];
      #pragma unroll
      for (int m = 0; m < 4; ++m){
        f32x4 vv = kv[m][n4];
        uint32_t p0 = cvt_pk_bf16(vv[0] + bias, vv[1] + bias);
        uint32_t p1 = cvt_pk_bf16(vv[2] + bias, vv[3] + bias);
        int tok0 = m * 16 + g * 4;
        *(short*)(smem + LDS_SK + swz256(tok0 + 0, feat * 2)) = (short)(p0);
        *(short*)(smem + LDS_SK + swz256(tok0 + 1, feat * 2)) = (short)(p0 >> 16);
        *(short*)(smem + LDS_SK + swz256(tok0 + 2, feat * 2)) = (short)(p1);
        *(short*)(smem + LDS_SK + swz256(tok0 + 3, feat * 2)) = (short)(p1 >> 16);
      }
    }
  } else {
    #pragma unroll
    for (int n4 = 0; n4 < 4; ++n4){
      int feat = (w - 2) * 64 + n4 * 16 + li;    // 0..127
      float bias = bqkv[2 * SF + feat];
      #pragma unroll
      for (int m = 0; m < 4; ++m){
        f32x4 vv = kv[m][n4];
        uint2 u;
        u.x = cvt_pk_bf16(vv[0] + bias, vv[1] + bias);
        u.y = cvt_pk_bf16(vv[2] + bias, vv[3] + bias);
        *(uint2*)(smem + LDS_SVT + swz128(feat, (m * 16 + g * 4) * 2)) = u;
      }
    }
  }
  __syncthreads();

  // ---------- Phase D: Q GEMM: [128 q] x [128 n] over K=256, 4 chunks of 64 ----------
  f32x4 qacc[8][2];
  #pragma unroll
  for (int m = 0; m < 8; ++m){ qacc[m][0] = vzero; qacc[m][1] = vzero; }

  const float* bx = big_x + (size_t)b * NB * BF + (size_t)hf * 128 * BF;
  const int qrow = t >> 1, qh32 = (t & 1) * 32;

  float4 ld[8];
  {
    const float4* s_ = (const float4*)(bx + qrow * BF + qh32);
    #pragma unroll
    for (int j = 0; j < 8; ++j) ld[j] = s_[j];
  }
  for (int kc = 0; kc < 4; ++kc){
    uint32_t pk[16];
    #pragma unroll
    for (int j = 0; j < 8; ++j){
      pk[2*j]   = cvt_pk_bf16(ld[j].x, ld[j].y);
      pk[2*j+1] = cvt_pk_bf16(ld[j].z, ld[j].w);
    }
    __syncthreads();   // prior chunk reads complete
    #pragma unroll
    for (int c = 0; c < 4; ++c){
      uint4 u; u.x = pk[c*4]; u.y = pk[c*4+1]; u.z = pk[c*4+2]; u.w = pk[c*4+3];
      *(uint4*)(smem + LDS_STG + swz128(qrow, qh32 * 2 + c * 16)) = u;
    }
    __syncthreads();   // chunk visible
    if (kc < 3){
      const float4* s_ = (const float4*)(bx + qrow * BF + (kc + 1) * 64 + qh32);
      #pragma unroll
      for (int j = 0; j < 8; ++j) ld[j] = s_[j];
    }
    #pragma unroll
    for (int ks = 0; ks < 2; ++ks){
      bf16x8 afr[8];
      #pragma unroll
      for (int m = 0; m < 8; ++m)
        afr[m] = *(const bf16x8*)(smem + LDS_STG + swz128(m*16 + li, (ks*32 + g*8) * 2));
      #pragma unroll
      for (int nt = 0; nt < 2; ++nt){
        int n = w * 32 + nt * 16 + li;
        bf16x8 bfr = *(const bf16x8*)(weffT + n * 256 + kc * 64 + ks * 32 + g * 8);
        #pragma unroll
        for (int m = 0; m < 8; ++m)
          qacc[m][nt] = __builtin_amdgcn_mfma_f32_16x16x32_bf16(afr[m], bfr, qacc[m][nt], 0, 0, 0);
      }
    }
  }

  // ---------- Phase D': Q (+beff) -> sQ bf16 swizzled ----------
  #pragma unroll
  for (int nt = 0; nt < 2; ++nt){
    int feat = w * 32 + nt * 16 + li;
    float be = beff[feat];
    #pragma unroll
    for (int m = 0; m < 8; ++m){
      f32x4 vv = qacc[m][nt];
      uint32_t p0 = cvt_pk_bf16(vv[0] + be, vv[1] + be);
      uint32_t p1 = cvt_pk_bf16(vv[2] + be, vv[3] + be);
      int r0 = m * 16 + g * 4;
      *(short*)(smem + LDS_SQ + swz256(r0 + 0, feat * 2)) = (short)(p0);
      *(short*)(smem + LDS_SQ + swz256(r0 + 1, feat * 2)) = (short)(p0 >> 16);
      *(short*)(smem + LDS_SQ + swz256(r0 + 2, feat * 2)) = (short)(p1);
      *(short*)(smem + LDS_SQ + swz256(r0 + 3, feat * 2)) = (short)(p1 >> 16);
    }
  }
  __syncthreads();

  // ---------- Phase E: S^T = K . Q^T for head h = w ; tiles 4(key) x 8(q), K=32 ----------
  f32x4 sacc[4][8];
  #pragma unroll
  for (int m = 0; m < 4; ++m)
    #pragma unroll
    for (int n = 0; n < 8; ++n) sacc[m][n] = vzero;
  {
    bf16x8 afr[4];
    #pragma unroll
    for (int m = 0; m < 4; ++m)
      afr[m] = *(const bf16x8*)(smem + LDS_SK + swz256(m*16 + li, (w*32 + g*8) * 2));
    #pragma unroll
    for (int n = 0; n < 8; ++n){
      bf16x8 bfr = *(const bf16x8*)(smem + LDS_SQ + swz256(n*16 + li, (w*32 + g*8) * 2));
      #pragma unroll
      for (int m = 0; m < 4; ++m)
        sacc[m][n] = __builtin_amdgcn_mfma_f32_16x16x32_bf16(afr[m], bfr, sacc[m][n], 0, 0, 0);
    }
  }
  __syncthreads();   // sQ/sK reads done -> sP region (sQ) reusable

  // bias add: element [key = m*16+g*4+r][q = hf*128 + n*16+li]
  {
    const float* bm = bmatT + w * (64 * 256);
    #pragma unroll
    for (int m = 0; m < 4; ++m){
      #pragma unroll
      for (int n = 0; n < 8; ++n){
        int qg = hf * 128 + n * 16 + li;
        #pragma unroll
        for (int r = 0; r < 4; ++r){
          int key = m * 16 + g * 4 + r;
          sacc[m][n][r] += bm[key * 256 + qg];
        }
      }
    }
  }

  // softmax over keys, per q (log2-domain; scale already folded)
  float sm[8];
  #pragma unroll
  for (int n = 0; n < 8; ++n){
    float mx = sacc[0][n][0];
    #pragma unroll
    for (int m = 0; m < 4; ++m)
      #pragma unroll
      for (int r = 0; r < 4; ++r) mx = fmaxf(mx, sacc[m][n][r]);
    mx = fmaxf(mx, __shfl_xor(mx, 16));
    mx = fmaxf(mx, __shfl_xor(mx, 32));
    float s0 = 0.f;
    #pragma unroll
    for (int m = 0; m < 4; ++m)
      #pragma unroll
      for (int r = 0; r < 4; ++r){
        float e = __builtin_amdgcn_exp2f(sacc[m][n][r] - mx);
        sacc[m][n][r] = e;
        s0 += e;
      }
    s0 += __shfl_xor(s0, 16);
    s0 += __shfl_xor(s0, 32);
    sm[n] = __builtin_amdgcn_rcpf(s0);
  }

  // ---------- Phase F: per q-half: P -> sP (wave-private), PV: O^T = V^T . P^T ----------
  f32x4 oacc[2][2][4];
  #pragma unroll
  for (int hl = 0; hl < 2; ++hl)
    #pragma unroll
    for (int m2 = 0; m2 < 2; ++m2)
      #pragma unroll
      for (int n4 = 0; n4 < 4; ++n4) oacc[hl][m2][n4] = vzero;

  char* sp = smem + LDS_SQ + w * 8192;   // wave-private 8KB: [64 q][64 key] bf16 swz128
  #pragma unroll
  for (int hl = 0; hl < 2; ++hl){
    #pragma unroll
    for (int n4 = 0; n4 < 4; ++n4){
      int n = hl * 4 + n4;
      #pragma unroll
      for (int m = 0; m < 4; ++m){
        uint2 u;
        u.x = cvt_pk_bf16(sacc[m][n][0], sacc[m][n][1]);
        u.y = cvt_pk_bf16(sacc[m][n][2], sacc[m][n][3]);
        *(uint2*)(sp + swz128(n4 * 16 + li, (m * 16 + g * 4) * 2)) = u;
      }
    }
    #pragma unroll
    for (int kk = 0; kk < 2; ++kk){
      bf16x8 afr[2];
      #pragma unroll
      for (int m2 = 0; m2 < 2; ++m2)
        afr[m2] = *(const bf16x8*)(smem + LDS_SVT + swz128(w*32 + m2*16 + li, (kk*32 + g*8) * 2));
      #pragma unroll
      for (int n4 = 0; n4 < 4; ++n4){
        bf16x8 bfr = *(const bf16x8*)(sp + swz128(n4 * 16 + li, (kk*32 + g*8) * 2));
        #pragma unroll
        for (int m2 = 0; m2 < 2; ++m2)
          oacc[hl][m2][n4] = __builtin_amdgcn_mfma_f32_16x16x32_bf16(afr[m2], bfr, oacc[hl][m2][n4], 0, 0, 0);
      }
    }
  }
  __syncthreads();   // all PV reads of sVT done -> sO may overwrite sK+sVT

  // O^T / sum -> sO [128 q][128 f] bf16 swz256 at LDS 0
  #pragma unroll
  for (int hl = 0; hl < 2; ++hl)
    #pragma unroll
    for (int m2 = 0; m2 < 2; ++m2)
      #pragma unroll
      for (int n4 = 0; n4 < 4; ++n4){
        float rs = sm[hl * 4 + n4];
        f32x4 vv = oacc[hl][m2][n4];
        uint2 u;
        u.x = cvt_pk_bf16(vv[0] * rs, vv[1] * rs);
        u.y = cvt_pk_bf16(vv[2] * rs, vv[3] * rs);
        *(uint2*)(smem + swz256(hl*64 + n4*16 + li, (w*32 + m2*16 + g*4) * 2)) = u;
      }
  __syncthreads();

  // ---------- Phase G: out = sO @ W2 + b2 : wave w -> cols w*64..w*64+63 ----------
  f32x4 facc[8][4];
  #pragma unroll
  for (int m = 0; m < 8; ++m)
    #pragma unroll
    for (int nt = 0; nt < 4; ++nt) facc[m][nt] = vzero;

  #pragma unroll
  for (int kc = 0; kc < 4; ++kc){
    bf16x8 afr[8];
    #pragma unroll
    for (int m = 0; m < 8; ++m)
      afr[m] = *(const bf16x8*)(smem + swz256(m*16 + li, (kc*32 + g*8) * 2));
    #pragma unroll
    for (int nt = 0; nt < 4; ++nt){
      int n = w * 64 + nt * 16 + li;
      bf16x8 bfr = *(const bf16x8*)(w2T + n * 128 + kc * 32 + g * 8);
      #pragma unroll
      for (int m = 0; m < 8; ++m)
        facc[m][nt] = __builtin_amdgcn_mfma_f32_16x16x32_bf16(afr[m], bfr, facc[m][nt], 0, 0, 0);
    }
  }

  float* op = out + (size_t)b * NB * BF + (size_t)hf * 128 * BF;
  #pragma unroll
  for (int nt = 0; nt < 4; ++nt){
    int col = w * 64 + nt * 16 + li;
    float bb = b2[col];
    #pragma unroll
    for (int m = 0; m < 8; ++m){
      int r0 = m * 16 + g * 4;
      #pragma unroll
      for (int r = 0; r < 4; ++r)
        op[(size_t)(r0 + r) * BF + col] = facc[m][nt][r] + bb;
    }
  }
}

extern "C" void kernel_launch(void* const* d_in, const int* in_sizes, int n_in,
                              void* d_out, int out_size, void* d_ws, size_t ws_size,
                              hipStream_t stream)
{
  const float* big_x   = (const float*)d_in[0];
  const float* small_x = (const float*)d_in[1];
  const float* W1      = (const float*)d_in[2];
  const float* b1      = (const float*)d_in[3];
  const float* Wqkv    = (const float*)d_in[4];
  const float* bqkv    = (const float*)d_in[5];
  const float* W2      = (const float*)d_in[6];
  const float* b2      = (const float*)d_in[7];
  const float* tbl     = (const float*)d_in[8];
  float* out = (float*)d_out;

  (void)in_sizes; (void)n_in; (void)out_size; (void)ws_size;

  cowin_prep<<<417, 256, 0, stream>>>(W1, b1, Wqkv, bqkv, W2, tbl, d_ws);

  hipFuncSetAttribute(reinterpret_cast<const void*>(cowin_main),
                      hipFuncAttributeMaxDynamicSharedMemorySize, LDS_TOTAL);
  cowin_main<<<NBATCH * 2, 256, LDS_TOTAL, stream>>>(big_x, small_x, bqkv, b2, d_ws, out);
}

// Round 2
// 179.326 us; speedup vs baseline: 1.0565x; 1.0565x over previous
//
#include <hip/hip_runtime.h>
#include <stdint.h>

// ---- problem constants ----
#define NH      4
#define SF      128
#define BF      256
#define HD      32
#define NB      256    // WU*WU big tokens
#define NS      64     // W*W small tokens
#define NBATCH  1024

typedef short bf16x8 __attribute__((ext_vector_type(8)));
typedef float f32x4  __attribute__((ext_vector_type(4)));

// ---- ws layout (bytes) ----
#define WEFFT_OFF 0        // short[128*256]  (WeffT[n][k], scale*log2e folded)
#define BEFF_OFF  65536    // float[128]
#define WKVT_OFF  66048    // short[256*128]  (WkvT[n][k]; n<128 K-proj, n>=128 V-proj)
#define W2T_OFF   131584   // short[256*128]  (W2T[n][k])
#define BMATT_OFF 197120   // float[4*64*256] (BmatT[h][key][q] * log2e)

// ---- LDS layout (bytes), total 65536 ----
#define LDS_SK  0          // 16KB: small_x stage -> K  [64 tok][128 f] bf16, swz256
#define LDS_SVT 16384      // 16KB: V^T [128 f][64 tok] bf16, swz128
#define LDS_SQ  32768      // 32KB: big_x stage dbuf (2x16KB) -> Q [128 q][128 f] swz256 -> P (8x4KB)
#define LDS_TOTAL 65536

__device__ __forceinline__ short f2b(float x){
  uint32_t u = __float_as_uint(x);
  u += 0x7fff + ((u >> 16) & 1);
  return (short)(u >> 16);
}
__device__ __forceinline__ uint32_t cvt_pk_bf16(float lo, float hi){
  uint32_t r;
  asm("v_cvt_pk_bf16_f32 %0, %1, %2" : "=v"(r) : "v"(lo), "v"(hi));
  return r;
}
__device__ __forceinline__ int swz256(int row, int byteInRow){
  return row * 256 + (byteInRow ^ ((row & 7) << 4));
}
__device__ __forceinline__ int swz128(int row, int byteInRow){
  return row * 128 + (byteInRow ^ ((row & 7) << 4));
}

// =====================================================================
// prep: WeffT = (W1 @ Wqkv[:, :SF])^T * SCALE*log2e (bf16),
//       beff, WkvT (bf16), W2T (bf16), BmatT[h][key][q]*log2e (f32)
// =====================================================================
__global__ void cowin_prep(const float* __restrict__ W1, const float* __restrict__ b1,
                           const float* __restrict__ Wqkv, const float* __restrict__ bqkv,
                           const float* __restrict__ W2, const float* __restrict__ tbl,
                           void* ws)
{
  short* weffT = (short*)((char*)ws + WEFFT_OFF);
  float* beff  = (float*)((char*)ws + BEFF_OFF);
  short* wkvT  = (short*)((char*)ws + WKVT_OFF);
  short* w2T   = (short*)((char*)ws + W2T_OFF);
  float* bmatT = (float*)((char*)ws + BMATT_OFF);
  const float L2E = 1.4426950408889634f;
  const float QS  = 0.17677669529663687f * L2E;   // HD^-0.5 * log2e

  int bid = blockIdx.x, t = threadIdx.x;
  if (bid < 128){                        // WeffT: n = bid, k = t
    int n = bid, k = t;
    float acc = 0.f;
    for (int c = 0; c < SF; ++c) acc += W1[k * SF + c] * Wqkv[c * (3*SF) + n];
    weffT[n * 256 + k] = f2b(acc * QS);
  } else if (bid == 128){
    if (t < 128){
      int n = t;
      float acc = bqkv[n];
      for (int c = 0; c < SF; ++c) acc += b1[c] * Wqkv[c * (3*SF) + n];
      beff[n] = acc * QS;
    }
  } else if (bid < 145){                 // WkvT: 32768 elems
    int base = (bid - 129) * 2048 + t * 8;
    for (int j = 0; j < 8; ++j){
      int i = base + j, n = i >> 7, k = i & 127;
      wkvT[i] = f2b(Wqkv[k * (3*SF) + SF + n]);
    }
  } else if (bid < 161){                 // W2T: 32768 elems
    int base = (bid - 145) * 2048 + t * 8;
    for (int j = 0; j < 8; ++j){
      int i = base + j, n = i >> 7, k = i & 127;
      w2T[i] = f2b(W2[k * BF + n]);
    }
  } else {                               // BmatT: 65536 elems
    int i = (bid - 161) * 256 + t;
    int h = i >> 14, kk = (i >> 8) & 63, q = i & 255;
    int qh = q >> 4, qw = q & 15, kh = kk >> 3, kw = kk & 7;
    int idx = (qh - kh + 7) * 15 + (qw - kw + 7);
    bmatT[i] = tbl[idx * 4 + h] * L2E;
  }
}

// =====================================================================
// fused main: one block = (batch b, row-half hf). 512 thr = 8 waves.
// attn phases: wave w -> head h = w&3, q-half qh = w>>2.
// =====================================================================
__global__ __launch_bounds__(512, 4) void cowin_main(
    const float* __restrict__ big_x, const float* __restrict__ small_x,
    const float* __restrict__ bqkv,  const float* __restrict__ b2,
    const void* __restrict__ ws, float* __restrict__ out)
{
  extern __shared__ char smem[];
  const short* weffT = (const short*)((const char*)ws + WEFFT_OFF);
  const float* beff  = (const float*)((const char*)ws + BEFF_OFF);
  const short* wkvT  = (const short*)((const char*)ws + WKVT_OFF);
  const short* w2T   = (const short*)((const char*)ws + W2T_OFF);
  const float* bmatT = (const float*)((const char*)ws + BMATT_OFF);

  const int bid = blockIdx.x;
  const int b  = bid >> 1;
  const int hf = bid & 1;
  const int t    = threadIdx.x;
  const int w    = t >> 6;          // wave id 0..7
  const int lane = t & 63;
  const int li   = lane & 15;       // within-tile row/col
  const int g    = lane >> 4;       // lane quarter

  const f32x4 vzero = {0.f, 0.f, 0.f, 0.f};

  const float* bx = big_x + (size_t)b * NB * BF + (size_t)hf * 128 * BF;
  const int qrow = t >> 2, qq = (t & 3) * 16;   // big staging: 16 floats/thread

  // ---------- Phase A: issue loads (small_x + big chunk0), stage small ----------
  float4 ld[4];
  {
    const float* sx = small_x + (size_t)b * (NS * SF);
    int tok = t >> 3, p = t & 7;
    const float4* src = (const float4*)(sx + tok * SF + p * 16);
    float4 sv[4];
    #pragma unroll
    for (int j = 0; j < 4; ++j) sv[j] = src[j];
    // early big_x chunk0 loads (latency hides under A/B/C)
    {
      const float4* s_ = (const float4*)(bx + qrow * BF + qq);
      #pragma unroll
      for (int j = 0; j < 4; ++j) ld[j] = s_[j];
    }
    uint32_t pk[8];
    #pragma unroll
    for (int j = 0; j < 4; ++j){
      pk[2*j]   = cvt_pk_bf16(sv[j].x, sv[j].y);
      pk[2*j+1] = cvt_pk_bf16(sv[j].z, sv[j].w);
    }
    #pragma unroll
    for (int c = 0; c < 2; ++c){
      uint4 u; u.x = pk[c*4]; u.y = pk[c*4+1]; u.z = pk[c*4+2]; u.w = pk[c*4+3];
      *(uint4*)(smem + LDS_SK + swz256(tok, p * 32 + c * 16)) = u;
    }
  }
  __syncthreads();

  // ---------- Phase B: KV GEMM: [64 tok] x [256 n]; wave w -> n in [w*32, w*32+32) ----------
  f32x4 kv[4][2];
  #pragma unroll
  for (int m = 0; m < 4; ++m){ kv[m][0] = vzero; kv[m][1] = vzero; }

  #pragma unroll
  for (int ks = 0; ks < 4; ++ks){
    bf16x8 afr[4];
    #pragma unroll
    for (int m = 0; m < 4; ++m)
      afr[m] = *(const bf16x8*)(smem + LDS_SK + swz256(m*16 + li, (ks*32 + g*8) * 2));
    #pragma unroll
    for (int n2 = 0; n2 < 2; ++n2){
      int n = w * 32 + n2 * 16 + li;
      bf16x8 bfr = *(const bf16x8*)(wkvT + n * 128 + ks * 32 + g * 8);
      #pragma unroll
      for (int m = 0; m < 4; ++m)
        kv[m][n2] = __builtin_amdgcn_mfma_f32_16x16x32_bf16(afr[m], bfr, kv[m][n2], 0, 0, 0);
    }
  }
  __syncthreads();   // all sX reads done; sK region may be overwritten

  // ---------- Phase C: waves 0-3 write K [tok][feat]; waves 4-7 write V^T [feat][tok] ----------
  if (w < 4){
    #pragma unroll
    for (int n2 = 0; n2 < 2; ++n2){
      int feat = w * 32 + n2 * 16 + li;          // 0..127
      float bias = bqkv[SF + feat];
      #pragma unroll
      for (int m = 0; m < 4; ++m){
        f32x4 vv = kv[m][n2];
        uint32_t p0 = cvt_pk_bf16(vv[0] + bias, vv[1] + bias);
        uint32_t p1 = cvt_pk_bf16(vv[2] + bias, vv[3] + bias);
        int tok0 = m * 16 + g * 4;
        *(short*)(smem + LDS_SK + swz256(tok0 + 0, feat * 2)) = (short)(p0);
        *(short*)(smem + LDS_SK + swz256(tok0 + 1, feat * 2)) = (short)(p0 >> 16);
        *(short*)(smem + LDS_SK + swz256(tok0 + 2, feat * 2)) = (short)(p1);
        *(short*)(smem + LDS_SK + swz256(tok0 + 3, feat * 2)) = (short)(p1 >> 16);
      }
    }
  } else {
    #pragma unroll
    for (int n2 = 0; n2 < 2; ++n2){
      int feat = (w - 4) * 32 + n2 * 16 + li;    // 0..127
      float bias = bqkv[2 * SF + feat];
      #pragma unroll
      for (int m = 0; m < 4; ++m){
        f32x4 vv = kv[m][n2];
        uint2 u;
        u.x = cvt_pk_bf16(vv[0] + bias, vv[1] + bias);
        u.y = cvt_pk_bf16(vv[2] + bias, vv[3] + bias);
        *(uint2*)(smem + LDS_SVT + swz128(feat, (m * 16 + g * 4) * 2)) = u;
      }
    }
  }
  // no barrier here: the first Phase-D barrier orders these writes before Phase E reads.

  // ---------- Phase D: Q GEMM [128 q]x[128 n] over K=256; 4 chunks of 64, LDS dbuf ----------
  f32x4 qacc[8];
  #pragma unroll
  for (int m = 0; m < 8; ++m) qacc[m] = vzero;

  // prologue: cvt+store chunk0 -> buf0, issue loads chunk1
  {
    uint32_t pk[8];
    #pragma unroll
    for (int j = 0; j < 4; ++j){
      pk[2*j]   = cvt_pk_bf16(ld[j].x, ld[j].y);
      pk[2*j+1] = cvt_pk_bf16(ld[j].z, ld[j].w);
    }
    char* buf0 = smem + LDS_SQ;
    #pragma unroll
    for (int c = 0; c < 2; ++c){
      uint4 u; u.x = pk[c*4]; u.y = pk[c*4+1]; u.z = pk[c*4+2]; u.w = pk[c*4+3];
      *(uint4*)(buf0 + swz128(qrow, qq * 2 + c * 16)) = u;
    }
    const float4* s_ = (const float4*)(bx + qrow * BF + 64 + qq);
    #pragma unroll
    for (int j = 0; j < 4; ++j) ld[j] = s_[j];
  }

  for (int kc = 0; kc < 4; ++kc){
    __syncthreads();   // buf[kc&1] visible; prior reads of buf[(kc+1)&1] done
    if (kc < 3){
      uint32_t pk[8];
      #pragma unroll
      for (int j = 0; j < 4; ++j){
        pk[2*j]   = cvt_pk_bf16(ld[j].x, ld[j].y);
        pk[2*j+1] = cvt_pk_bf16(ld[j].z, ld[j].w);
      }
      char* bufn = smem + LDS_SQ + ((kc + 1) & 1) * 16384;
      #pragma unroll
      for (int c = 0; c < 2; ++c){
        uint4 u; u.x = pk[c*4]; u.y = pk[c*4+1]; u.z = pk[c*4+2]; u.w = pk[c*4+3];
        *(uint4*)(bufn + swz128(qrow, qq * 2 + c * 16)) = u;
      }
      if (kc < 2){
        const float4* s_ = (const float4*)(bx + qrow * BF + (kc + 2) * 64 + qq);
        #pragma unroll
        for (int j = 0; j < 4; ++j) ld[j] = s_[j];
      }
    }
    const char* buf = smem + LDS_SQ + (kc & 1) * 16384;
    const int n = w * 16 + li;
    #pragma unroll
    for (int ks = 0; ks < 2; ++ks){
      bf16x8 afr[8];
      #pragma unroll
      for (int m = 0; m < 8; ++m)
        afr[m] = *(const bf16x8*)(buf + swz128(m*16 + li, (ks*32 + g*8) * 2));
      bf16x8 bfr = *(const bf16x8*)(weffT + n * 256 + kc * 64 + ks * 32 + g * 8);
      #pragma unroll
      for (int m = 0; m < 8; ++m)
        qacc[m] = __builtin_amdgcn_mfma_f32_16x16x32_bf16(afr[m], bfr, qacc[m], 0, 0, 0);
    }
  }
  __syncthreads();   // all stage-buffer reads done; sQ region may be overwritten

  // ---------- Phase D': Q (+beff) -> sQ [128 q][128 f] bf16 swz256 ----------
  {
    int feat = w * 16 + li;
    float be = beff[feat];
    #pragma unroll
    for (int m = 0; m < 8; ++m){
      f32x4 vv = qacc[m];
      uint32_t p0 = cvt_pk_bf16(vv[0] + be, vv[1] + be);
      uint32_t p1 = cvt_pk_bf16(vv[2] + be, vv[3] + be);
      int r0 = m * 16 + g * 4;
      *(short*)(smem + LDS_SQ + swz256(r0 + 0, feat * 2)) = (short)(p0);
      *(short*)(smem + LDS_SQ + swz256(r0 + 1, feat * 2)) = (short)(p0 >> 16);
      *(short*)(smem + LDS_SQ + swz256(r0 + 2, feat * 2)) = (short)(p1);
      *(short*)(smem + LDS_SQ + swz256(r0 + 3, feat * 2)) = (short)(p1 >> 16);
    }
  }
  __syncthreads();

  // ---------- Phase E: S^T = K . Q^T ; wave = (head h, q-half qh): 4(key) x 4(q) tiles ----------
  const int h  = w & 3;
  const int qh = w >> 2;
  f32x4 sacc[4][4];
  #pragma unroll
  for (int m = 0; m < 4; ++m)
    #pragma unroll
    for (int n = 0; n < 4; ++n) sacc[m][n] = vzero;
  {
    bf16x8 afr[4];
    #pragma unroll
    for (int m = 0; m < 4; ++m)
      afr[m] = *(const bf16x8*)(smem + LDS_SK + swz256(m*16 + li, (h*32 + g*8) * 2));
    #pragma unroll
    for (int n = 0; n < 4; ++n){
      bf16x8 bfr = *(const bf16x8*)(smem + LDS_SQ + swz256(qh*64 + n*16 + li, (h*32 + g*8) * 2));
      #pragma unroll
      for (int m = 0; m < 4; ++m)
        sacc[m][n] = __builtin_amdgcn_mfma_f32_16x16x32_bf16(afr[m], bfr, sacc[m][n], 0, 0, 0);
    }
  }
  __syncthreads();   // sQ/sK reads done -> sQ region reusable for P

  // bias add: element [key = m*16+g*4+r][q = hf*128 + qh*64 + n*16+li]
  {
    const float* bm = bmatT + h * (64 * 256);
    #pragma unroll
    for (int m = 0; m < 4; ++m){
      #pragma unroll
      for (int n = 0; n < 4; ++n){
        int qg = hf * 128 + qh * 64 + n * 16 + li;
        #pragma unroll
        for (int r = 0; r < 4; ++r){
          int key = m * 16 + g * 4 + r;
          sacc[m][n][r] += bm[key * 256 + qg];
        }
      }
    }
  }

  // softmax over keys, per q (log2-domain; scale folded)
  float sm[4];
  #pragma unroll
  for (int n = 0; n < 4; ++n){
    float mx = sacc[0][n][0];
    #pragma unroll
    for (int m = 0; m < 4; ++m)
      #pragma unroll
      for (int r = 0; r < 4; ++r) mx = fmaxf(mx, sacc[m][n][r]);
    mx = fmaxf(mx, __shfl_xor(mx, 16));
    mx = fmaxf(mx, __shfl_xor(mx, 32));
    float s0 = 0.f;
    #pragma unroll
    for (int m = 0; m < 4; ++m)
      #pragma unroll
      for (int r = 0; r < 4; ++r){
        float e = __builtin_amdgcn_exp2f(sacc[m][n][r] - mx);
        sacc[m][n][r] = e;
        s0 += e;
      }
    s0 += __shfl_xor(s0, 16);
    s0 += __shfl_xor(s0, 32);
    sm[n] = __builtin_amdgcn_rcpf(s0);
  }

  // ---------- Phase F: per 32-q half: P -> sP (wave-private 4KB), PV: O^T = V^T . P^T ----------
  f32x4 oacc[2][2][2];
  #pragma unroll
  for (int hl = 0; hl < 2; ++hl)
    #pragma unroll
    for (int m2 = 0; m2 < 2; ++m2)
      #pragma unroll
      for (int n4 = 0; n4 < 2; ++n4) oacc[hl][m2][n4] = vzero;

  char* sp = smem + LDS_SQ + w * 4096;   // wave-private 4KB: [32 q][64 key] bf16 swz128
  #pragma unroll
  for (int hl = 0; hl < 2; ++hl){
    #pragma unroll
    for (int n4 = 0; n4 < 2; ++n4){
      int n = hl * 2 + n4;
      #pragma unroll
      for (int m = 0; m < 4; ++m){
        uint2 u;
        u.x = cvt_pk_bf16(sacc[m][n][0], sacc[m][n][1]);
        u.y = cvt_pk_bf16(sacc[m][n][2], sacc[m][n][3]);
        *(uint2*)(sp + swz128(n4 * 16 + li, (m * 16 + g * 4) * 2)) = u;
      }
    }
    #pragma unroll
    for (int kk = 0; kk < 2; ++kk){
      bf16x8 afr[2];
      #pragma unroll
      for (int m2 = 0; m2 < 2; ++m2)
        afr[m2] = *(const bf16x8*)(smem + LDS_SVT + swz128(h*32 + m2*16 + li, (kk*32 + g*8) * 2));
      #pragma unroll
      for (int n4 = 0; n4 < 2; ++n4){
        bf16x8 bfr = *(const bf16x8*)(sp + swz128(n4 * 16 + li, (kk*32 + g*8) * 2));
        #pragma unroll
        for (int m2 = 0; m2 < 2; ++m2)
          oacc[hl][m2][n4] = __builtin_amdgcn_mfma_f32_16x16x32_bf16(afr[m2], bfr, oacc[hl][m2][n4], 0, 0, 0);
      }
    }
  }
  __syncthreads();   // all PV reads of sVT done -> sO may overwrite sK+sVT

  // O^T / sum -> sO [128 q][128 f] bf16 swz256 at LDS 0
  #pragma unroll
  for (int hl = 0; hl < 2; ++hl)
    #pragma unroll
    for (int m2 = 0; m2 < 2; ++m2)
      #pragma unroll
      for (int n4 = 0; n4 < 2; ++n4){
        float rs = sm[hl * 2 + n4];
        f32x4 vv = oacc[hl][m2][n4];
        uint2 u;
        u.x = cvt_pk_bf16(vv[0] * rs, vv[1] * rs);
        u.y = cvt_pk_bf16(vv[2] * rs, vv[3] * rs);
        int q = qh * 64 + hl * 32 + n4 * 16 + li;
        *(uint2*)(smem + swz256(q, (h*32 + m2*16 + g*4) * 2)) = u;
      }
  __syncthreads();

  // ---------- Phase G: out = sO @ W2 + b2 : wave w -> cols [w*32, w*32+32) ----------
  f32x4 facc[8][2];
  #pragma unroll
  for (int m = 0; m < 8; ++m){ facc[m][0] = vzero; facc[m][1] = vzero; }

  #pragma unroll
  for (int kc = 0; kc < 4; ++kc){
    bf16x8 afr[8];
    #pragma unroll
    for (int m = 0; m < 8; ++m)
      afr[m] = *(const bf16x8*)(smem + swz256(m*16 + li, (kc*32 + g*8) * 2));
    #pragma unroll
    for (int nt = 0; nt < 2; ++nt){
      int n = w * 32 + nt * 16 + li;
      bf16x8 bfr = *(const bf16x8*)(w2T + n * 128 + kc * 32 + g * 8);
      #pragma unroll
      for (int m = 0; m < 8; ++m)
        facc[m][nt] = __builtin_amdgcn_mfma_f32_16x16x32_bf16(afr[m], bfr, facc[m][nt], 0, 0, 0);
    }
  }

  float* op = out + (size_t)b * NB * BF + (size_t)hf * 128 * BF;
  #pragma unroll
  for (int nt = 0; nt < 2; ++nt){
    int col = w * 32 + nt * 16 + li;
    float bb = b2[col];
    #pragma unroll
    for (int m = 0; m < 8; ++m){
      int r0 = m * 16 + g * 4;
      #pragma unroll
      for (int r = 0; r < 4; ++r)
        op[(size_t)(r0 + r) * BF + col] = facc[m][nt][r] + bb;
    }
  }
}

extern "C" void kernel_launch(void* const* d_in, const int* in_sizes, int n_in,
                              void* d_out, int out_size, void* d_ws, size_t ws_size,
                              hipStream_t stream)
{
  const float* big_x   = (const float*)d_in[0];
  const float* small_x = (const float*)d_in[1];
  const float* W1      = (const float*)d_in[2];
  const float* b1      = (const float*)d_in[3];
  const float* Wqkv    = (const float*)d_in[4];
  const float* bqkv    = (const float*)d_in[5];
  const float* W2      = (const float*)d_in[6];
  const float* b2      = (const float*)d_in[7];
  const float* tbl     = (const float*)d_in[8];
  float* out = (float*)d_out;

  (void)in_sizes; (void)n_in; (void)out_size; (void)ws_size;

  cowin_prep<<<417, 256, 0, stream>>>(W1, b1, Wqkv, bqkv, W2, tbl, d_ws);

  hipFuncSetAttribute(reinterpret_cast<const void*>(cowin_main),
                      hipFuncAttributeMaxDynamicSharedMemorySize, LDS_TOTAL);
  cowin_main<<<NBATCH * 2, 512, LDS_TOTAL, stream>>>(big_x, small_x, bqkv, b2, d_ws, out);
}